// Round 6
// baseline (181.802 us; speedup 1.0000x reference)
//
#include <hip/hip_runtime.h>
#include <cstdint>

typedef __attribute__((ext_vector_type(8))) short short8;     // 8 bf16 (4 VGPRs)
typedef __attribute__((ext_vector_type(4))) float floatx4;
typedef __attribute__((ext_vector_type(2))) unsigned int uintx2;
typedef __attribute__((ext_vector_type(4))) unsigned int uintx4;

__device__ __forceinline__ uint32_t pack2(float a, float b) {
    uint32_t ua = __builtin_bit_cast(uint32_t, a);
    uint32_t ub = __builtin_bit_cast(uint32_t, b);
    ua = (ua + 0x7FFFu + ((ua >> 16) & 1u)) >> 16;   // RNE (verified, absmax 0.5)
    ub = (ub + 0x7FFFu + ((ub >> 16) & 1u)) >> 16;
    return ua | (ub << 16);                           // lo = even channel, hi = odd channel
}

// =====================================================================
// PASS 1 (unchanged from R5, verified, ~12 us): f2 -> t2p bf16-kpair,
// channel-chunk-outer: t2p[cc2][b][h][wp 0..143][word 0..15]; W pad +-4;
// 4KB zero stripe at the end.
// =====================================================================
#define CC_SLAB  ((size_t)8 * 64 * 2304)          // words per cc2 slab
#define T2P_WORDS (8 * CC_SLAB)                   // 9,437,184 words = 36 MiB
#define WS_NEED   (T2P_WORDS * 4 + 4096)

__global__ __launch_bounds__(256)
void transpose_f2(const float* __restrict__ f2, uint32_t* __restrict__ t2p) {
    __shared__ float t[64][33];
    const int tid = threadIdx.x;
    const int bid = blockIdx.x;                   // 8b x 64h x 4wt = 2048
    const int b = bid & 7, h = (bid >> 3) & 63, wt = bid >> 9;
    const int w0 = wt * 32;
    const float* f2b = f2 + (size_t)b * 256 * 8192 + (size_t)h * 128 + w0;

    const int rw = tid & 31, rc8 = tid >> 5;      // read: w lane, ch-group
    const int tp = tid & 127, rr = tid >> 7;      // write: region rr, tp 0..127
    const int m  = tp & 15;                        // word-in-cell (= kp & 15)

    for (int cc = 0; cc < 4; ++cc) {
        if (cc) __syncthreads();
#pragma unroll
        for (int i = 0; i < 8; ++i)
            t[rc8 * 8 + i][rw] = f2b[(size_t)(cc * 64 + rc8 * 8 + i) * 8192 + rw];
        __syncthreads();
        const int cc2 = 2 * cc + rr;
        uint32_t* dst = t2p + (size_t)cc2 * CC_SLAB
                        + ((size_t)b * 64 + h) * 2304 + (size_t)(w0 + 4) * 16;
#pragma unroll
        for (int i = 0; i < 4; ++i) {
            int d = i * 128 + tp;                  // 512B contiguous per instr
            int j = d >> 4;
            dst[d] = pack2(t[rr * 32 + 2 * m][j], t[rr * 32 + 2 * m + 1][j]);
        }
    }
    if (wt == 0) {
        for (int idx = tid; idx < 512; idx += 256) {
            int cc2 = idx >> 6, o = idx & 63;
            t2p[(size_t)cc2 * CC_SLAB + ((size_t)b * 64 + h) * 2304 + o] = 0;
        }
    }
    if (wt == 3) {
        for (int idx = tid; idx < 1536; idx += 256) {
            int cc2 = idx / 192, o = idx % 192;
            t2p[(size_t)cc2 * CC_SLAB + ((size_t)b * 64 + h) * 2304 + 132 * 16 + o] = 0;
        }
    }
    if (bid == 0) {
        uint32_t* z = t2p + T2P_WORDS;
        for (int idx = tid; idx < 1024; idx += 256) z[idx] = 0;
    }
}

// =====================================================================
// PASS 2 v4 (corr3): 1024-thread block = 16h x 16w tile (halo overlap
// 2.0 -> 1.5), 24-cell staging (cuts the 25% dead-cell waste), 4 LDS
// buffers (B lookahead 3, A lookahead 2, counted vmcnt 14/11/0),
// rotation restored (R4's measured +10us demand-smoothing lever).
// B re-read volume: 131 MB -> 74 MB.
// =====================================================================
#define AS1 __attribute__((address_space(1)))
#define AS3 __attribute__((address_space(3)))

__device__ __forceinline__ void gld_lds16(const uint32_t* src, uint32_t* dst) {
    __builtin_amdgcn_global_load_lds((const AS1 void*)src, (AS3 void*)dst, 16, 0, 0);
}

#define BUF_WORDS 9216            // 24 rows x 24 cells x 16 words (36 KB)
#define DUMP_OFF  (4 * BUF_WORDS) // shared dump cell for dummy slots

__global__ __launch_bounds__(1024, 4)   // 16 waves/CU requires <=128 regs
void corr3(const float* __restrict__ f1, const uint32_t* __restrict__ t2p,
           const uint32_t* __restrict__ wsZ, float* __restrict__ out) {
    __shared__ uint32_t ldsB[4 * BUF_WORDS + 256];   // 148.5 KB, 1 block/CU

    const int tid  = threadIdx.x;
    const int lane = tid & 63;
    const int wh   = tid >> 6;                    // wave id == h sub-row (0..15)
    const int n15  = lane & 15;
    const int q    = lane >> 4;

    const int bid = blockIdx.x;                   // 8b x 4ht x 8wt = 256 (1/CU)
    const int b  = bid & 7;                       // XCD = batch
    const int ht = (bid >> 3) & 3;
    const int wt = bid >> 5;
    const int h0 = 16 * ht, w0 = 16 * wt;
    const int h  = h0 + wh;
    const int p  = (ht + wt) & 7;                 // channel-phase rotation

    const float* f1b = f1 + (size_t)b * 256 * 8192;

    // ---- B staging: 24 rows x 24 cells = 576 cells = 36 slots of 1KB.
    // 48 slot positions (3/wave); sg%4==3 -> dummy (stripe->dump), keeps
    // per-wave vmcnt uniform. Addressing via u32 offsets from t2p (reg save).
    uint32_t bOff[3], ccMul[3];
    int bOffL[3];
    bool dumpf[3];
#pragma unroll
    for (int s = 0; s < 3; ++s) {
        int sg = wh * 3 + s;                      // 0..47
        bool dummy = (sg & 3) == 3;
        int rank = (sg >> 2) * 3 + (sg & 3);      // 0..35, bijective for real
        int f = rank * 16 + (lane >> 2);          // flat cell 0..575
        int r = f / 24, cidx = f % 24;            // row (halo), cell col
        int gh = h0 - 4 + r;
        int gd = (lane & 3) ^ ((cidx >> 1) & 3);  // quarter swizzle (verified)
        bool inb = !dummy && ((unsigned)gh < 64u);
        bOff[s]  = inb ? (uint32_t)((b * 64 + gh) * 2304 + (w0 + cidx) * 16 + gd * 4)
                       : (uint32_t)(T2P_WORDS + lane * 4);   // zero stripe
        ccMul[s] = inb ? (uint32_t)CC_SLAB : 0u;
        bOffL[s] = rank * 256;
        dumpf[s] = dummy;
    }

    // ---- A: lane (n15,q) covers (h, w0+n15), channels 32cc+8q+j
    const float* aBase = f1b + (size_t)h * 128 + w0 + n15;

    floatx4 acc[9][2];
#pragma unroll
    for (int di = 0; di < 9; ++di)
#pragma unroll
        for (int t = 0; t < 2; ++t)
            acc[di][t] = (floatx4){0.f, 0.f, 0.f, 0.f};

    const int rdB = n15 * 16 + ((q ^ ((n15 >> 1) & 3)) << 2);

    auto stageB = [&](int bufsel, int cc) {       // 3 gld_lds16 per wave
        uint32_t* dbase = ldsB + bufsel * BUF_WORDS;
#pragma unroll
        for (int s = 0; s < 3; ++s) {
            const uint32_t* src = t2p + (size_t)(bOff[s] + (uint32_t)cc * ccMul[s]);
            uint32_t* d = dumpf[s] ? (ldsB + DUMP_OFF) : (dbase + bOffL[s]);
            gld_lds16(src, d);
        }
    };
    auto loadA = [&](float* r, int cc) {          // 8 dword loads per lane
        const float* ap = aBase + (size_t)(32 * cc + 8 * q) * 8192;
#pragma unroll
        for (int j = 0; j < 8; ++j) r[j] = ap[(size_t)j * 8192];
    };
    auto packA = [&](const float* r) -> short8 {
        uintx4 av = {pack2(r[0], r[1]), pack2(r[2], r[3]),
                     pack2(r[4], r[5]), pack2(r[6], r[7])};
        return __builtin_bit_cast(short8, av);
    };
    auto mfma9 = [&](int bufsel, short8 a0) {
        const uint32_t* bufB = ldsB + bufsel * BUF_WORDS;
#pragma unroll
        for (int di = 0; di < 9; ++di) {
            const uint32_t* p0 = bufB + (wh + di) * 384 + rdB;   // rows 0..23
            uintx4 v0 = *(const uintx4*)p0;                      // cell n15
            uintx4 v1 = *(const uintx4*)(p0 + 128);              // cell n15+8
            short8 b0 = __builtin_bit_cast(short8, v0);
            short8 b1 = __builtin_bit_cast(short8, v1);
            acc[di][0] = __builtin_amdgcn_mfma_f32_16x16x32_bf16(a0, b0, acc[di][0], 0, 0, 0);
            acc[di][1] = __builtin_amdgcn_mfma_f32_16x16x32_bf16(a0, b1, acc[di][1], 0, 0, 0);
        }
    };

    float rA0[8], rA1[8];
#define ROT(t) (((t) + p) & 7)
#define SB __builtin_amdgcn_sched_barrier(0)

    // prologue FIFO: A0(8) B0(3) A1(8) B1(3) B2(3) = 25 outstanding
    loadA(rA0, ROT(0)); SB;
    stageB(0, ROT(0)); SB;
    loadA(rA1, ROT(1)); SB;
    stageB(1, ROT(1)); SB;
    stageB(2, ROT(2)); SB;

    // Chunk K: vmcnt drains A(K),B(K) exactly (FIFO-derived: 14,...,14,11,0).
    // Body: pack A(K); reload set for A(K+2); stage B(K+3) into the buffer
    // freed at this barrier (read at K-1); compute buf K&3.
#define CHUNK(K, VM, RS)                                                      \
    {                                                                         \
        asm volatile("s_waitcnt vmcnt(" #VM ")\n\ts_barrier" ::: "memory");   \
        short8 a0 = packA(RS);                                                \
        SB;                                                                   \
        if ((K) <= 5) loadA(RS, ROT((K) + 2));                                \
        SB;                                                                   \
        if ((K) <= 4) stageB(((K) + 3) & 3, ROT((K) + 3));                    \
        SB;                                                                   \
        mfma9((K) & 3, a0);                                                   \
    }

    CHUNK(0, 14, rA0)
    CHUNK(1, 14, rA1)
    CHUNK(2, 14, rA0)
    CHUNK(3, 14, rA1)
    CHUNK(4, 14, rA0)
    CHUNK(5, 14, rA1)
    CHUNK(6, 11, rA0)
    CHUNK(7, 0,  rA1)
#undef CHUNK
#undef ROT
#undef SB

    // ---- epilogue: band extraction (verified). dj = t*8 + n15 - mp; t1 stores n15>=8.
    const size_t base = ((size_t)b * 81) * 8192 + (size_t)h * 128 + w0;
#pragma unroll
    for (int di = 0; di < 9; ++di) {
#pragma unroll
        for (int t = 0; t < 2; ++t) {
#pragma unroll
            for (int r = 0; r < 4; ++r) {
                int mp = 4 * q + r;
                int dj = t * 8 + n15 - mp;
                if (dj >= 0 && dj <= 8 && (t == 0 || n15 >= 8)) {
                    out[base + (size_t)(di * 9 + dj) * 8192 + mp] = acc[di][t][r];
                }
            }
        }
    }
}

// =====================================================================
// FALLBACK (verified R2 kernel) — used only if workspace is too small.
// =====================================================================
#define CS 18
#define A_WORDS (8 * 16 * CS)
#define B_ROWS  13
#define B_WORDS (B_ROWS * 24 * CS)

__device__ __forceinline__ short8 frag_ld(const uint32_t* p) {
    uintx2 lo = *(const uintx2*)p;
    uintx2 hi = *(const uintx2*)(p + 2);
    uintx4 v = {lo.x, lo.y, hi.x, hi.y};
    return __builtin_bit_cast(short8, v);
}

__global__ __launch_bounds__(512, 4)
void corr_kernel(const float* __restrict__ f1, const float* __restrict__ f2,
                 float* __restrict__ out) {
    __shared__ uint32_t ldsA[2 * A_WORDS];
    __shared__ uint32_t ldsB2[2 * B_WORDS];

    const int tid  = threadIdx.x;
    const int lane = tid & 63;
    const int wh   = tid >> 6;
    const int n15  = lane & 15;
    const int q    = lane >> 4;

    const int bid    = blockIdx.x;
    const int b      = bid & 7;
    const int dihalf = (bid >> 3) & 1;
    const int ht     = (bid >> 4) & 7;
    const int wt     = bid >> 7;

    const int w0 = wt * 16;
    const int h0 = ht * 8;
    const int h  = h0 + wh;

    const int diN    = dihalf ? 4 : 5;
    const int diBase = dihalf * 5;
    const int ghBase = dihalf ? (h0 + 1) : (h0 - 4);

    const float* f1b = f1 + (size_t)b * 256 * 8192;
    const float* f2b = f2 + (size_t)b * 256 * 8192;

    const int aw4 = tid & 3, akp = (tid >> 2) & 15, arow = tid >> 6;
    int aOffG = (2 * akp) * 8192 + (h0 + arow) * 128 + (w0 + 4 * aw4);
    const int aLds = (arow * 16 + 4 * aw4) * CS + akp;

    int bOffG[3]; int bLds[3]; uint32_t bMask[3];
#pragma unroll
    for (int s = 0; s < 3; ++s) {
        int t = tid + 512 * s;
        int w4 = t % 6;
        int r2 = t / 6;
        int kp = r2 & 15, row = r2 >> 4;
        int gh = ghBase + row;
        int gw = w0 - 4 + 4 * w4;
        bool live = (t < 1152);
        bool inb  = live && ((unsigned)gh < 64u) && ((unsigned)gw < 128u);
        bOffG[s] = inb ? ((2 * kp) * 8192 + gh * 128 + gw) : 0;
        bLds[s]  = live ? ((row * 24 + 4 * w4) * CS + kp) : ((12 * 24 + (tid & 7)) * CS);
        bMask[s] = inb ? 0xFFFFFFFFu : 0u;
    }

    floatx4 acc[5][2];
#pragma unroll
    for (int dl = 0; dl < 5; ++dl)
#pragma unroll
        for (int t = 0; t < 2; ++t)
            acc[dl][t] = (floatx4){0.f, 0.f, 0.f, 0.f};

    floatx4 rA[2], rB[3][2];
    uint32_t pkA[4], pkB[12];

    auto issue = [&]() {
        rA[0] = *(const floatx4*)(f1b + aOffG);
        rA[1] = *(const floatx4*)(f1b + aOffG + 8192);
        aOffG += 32 * 8192;
#pragma unroll
        for (int s = 0; s < 3; ++s) {
            rB[s][0] = *(const floatx4*)(f2b + bOffG[s]);
            rB[s][1] = *(const floatx4*)(f2b + bOffG[s] + 8192);
            bOffG[s] += 32 * 8192;
        }
    };
    auto packall = [&]() {
#pragma unroll
        for (int i = 0; i < 4; ++i) pkA[i] = pack2(rA[0][i], rA[1][i]);
#pragma unroll
        for (int s = 0; s < 3; ++s)
#pragma unroll
            for (int i = 0; i < 4; ++i)
                pkB[4 * s + i] = pack2(rB[s][0][i], rB[s][1][i]) & bMask[s];
    };

    issue(); packall();

    for (int ch = 0; ch < 8; ++ch) {
        uint32_t* bufA = ldsA + (ch & 1) * A_WORDS;
        uint32_t* bufB = ldsB2 + (ch & 1) * B_WORDS;
#pragma unroll
        for (int i = 0; i < 4; ++i) bufA[aLds + i * CS] = pkA[i];
#pragma unroll
        for (int s = 0; s < 3; ++s)
#pragma unroll
            for (int i = 0; i < 4; ++i) bufB[bLds[s] + i * CS] = pkB[4 * s + i];
        if (ch < 7) issue();
        __syncthreads();

        const uint32_t* pa = bufA + (wh * 16 + n15) * CS + 4 * q;
        short8 a0 = frag_ld(pa);
        const uint32_t* pb = bufB + (wh * 24 + n15) * CS + 4 * q;
#pragma unroll
        for (int dl = 0; dl < 5; ++dl) {
            if (dl < diN) {
                const uint32_t* pp = pb + dl * (24 * CS);
                short8 b0 = frag_ld(pp);
                short8 b1 = frag_ld(pp + 8 * CS);
                acc[dl][0] = __builtin_amdgcn_mfma_f32_16x16x32_bf16(a0, b0, acc[dl][0], 0, 0, 0);
                acc[dl][1] = __builtin_amdgcn_mfma_f32_16x16x32_bf16(a0, b1, acc[dl][1], 0, 0, 0);
            }
        }
        if (ch < 7) packall();
    }

    const size_t base = ((size_t)b * 81) * 8192 + (size_t)h * 128 + w0;
#pragma unroll
    for (int dl = 0; dl < 5; ++dl) {
        if (dl < diN) {
            const int dio = diBase + dl;
#pragma unroll
            for (int t = 0; t < 2; ++t) {
#pragma unroll
                for (int r = 0; r < 4; ++r) {
                    int mp = 4 * q + r;
                    int dj = t * 8 + n15 - mp;
                    if (dj >= 0 && dj <= 8 && (t == 0 || n15 >= 8)) {
                        out[base + (size_t)(dio * 9 + dj) * 8192 + mp] = acc[dl][t][r];
                    }
                }
            }
        }
    }
}

extern "C" void kernel_launch(void* const* d_in, const int* in_sizes, int n_in,
                              void* d_out, int out_size, void* d_ws, size_t ws_size,
                              hipStream_t stream) {
    const float* f1 = (const float*)d_in[0];
    const float* f2 = (const float*)d_in[1];
    float* out = (float*)d_out;
    if (ws_size >= WS_NEED && d_ws != nullptr) {
        uint32_t* t2p = (uint32_t*)d_ws;
        transpose_f2<<<dim3(2048), dim3(256), 0, stream>>>(f2, t2p);
        corr3<<<dim3(256), dim3(1024), 0, stream>>>(f1, t2p, t2p + T2P_WORDS, out);
    } else {
        corr_kernel<<<dim3(1024), dim3(512), 0, stream>>>(f1, f2, out);
    }
}

// Round 7
// 179.836 us; speedup vs baseline: 1.0109x; 1.0109x over previous
//
#include <hip/hip_runtime.h>
#include <cstdint>

typedef __attribute__((ext_vector_type(8))) short short8;     // 8 bf16 (4 VGPRs)
typedef __attribute__((ext_vector_type(4))) float floatx4;
typedef __attribute__((ext_vector_type(2))) unsigned int uintx2;
typedef __attribute__((ext_vector_type(4))) unsigned int uintx4;

__device__ __forceinline__ uint32_t pack2(float a, float b) {
    uint32_t ua = __builtin_bit_cast(uint32_t, a);
    uint32_t ub = __builtin_bit_cast(uint32_t, b);
    ua = (ua + 0x7FFFu + ((ua >> 16) & 1u)) >> 16;   // RNE (verified, absmax 0.5)
    ub = (ub + 0x7FFFu + ((ub >> 16) & 1u)) >> 16;
    return ua | (ub << 16);                           // lo = even channel, hi = odd channel
}

// =====================================================================
// PASS 1 (unchanged, verified, ~12 us): f2 -> t2p bf16-kpair,
// channel-chunk-outer: t2p[cc2][b][h][wp 0..143][word 0..15]; W pad +-4;
// 4KB zero stripe at the end.
// =====================================================================
#define CC_SLAB  ((size_t)8 * 64 * 2304)          // words per cc2 slab
#define T2P_WORDS (8 * CC_SLAB)                   // 9,437,184 words = 36 MiB
#define WS_NEED   (T2P_WORDS * 4 + 4096)

__global__ __launch_bounds__(256)
void transpose_f2(const float* __restrict__ f2, uint32_t* __restrict__ t2p) {
    __shared__ float t[64][33];
    const int tid = threadIdx.x;
    const int bid = blockIdx.x;                   // 8b x 64h x 4wt = 2048
    const int b = bid & 7, h = (bid >> 3) & 63, wt = bid >> 9;
    const int w0 = wt * 32;
    const float* f2b = f2 + (size_t)b * 256 * 8192 + (size_t)h * 128 + w0;

    const int rw = tid & 31, rc8 = tid >> 5;      // read: w lane, ch-group
    const int tp = tid & 127, rr = tid >> 7;      // write: region rr, tp 0..127
    const int m  = tp & 15;                        // word-in-cell (= kp & 15)

    for (int cc = 0; cc < 4; ++cc) {
        if (cc) __syncthreads();
#pragma unroll
        for (int i = 0; i < 8; ++i)
            t[rc8 * 8 + i][rw] = f2b[(size_t)(cc * 64 + rc8 * 8 + i) * 8192 + rw];
        __syncthreads();
        const int cc2 = 2 * cc + rr;
        uint32_t* dst = t2p + (size_t)cc2 * CC_SLAB
                        + ((size_t)b * 64 + h) * 2304 + (size_t)(w0 + 4) * 16;
#pragma unroll
        for (int i = 0; i < 4; ++i) {
            int d = i * 128 + tp;                  // 512B contiguous per instr
            int j = d >> 4;
            dst[d] = pack2(t[rr * 32 + 2 * m][j], t[rr * 32 + 2 * m + 1][j]);
        }
    }
    if (wt == 0) {
        for (int idx = tid; idx < 512; idx += 256) {
            int cc2 = idx >> 6, o = idx & 63;
            t2p[(size_t)cc2 * CC_SLAB + ((size_t)b * 64 + h) * 2304 + o] = 0;
        }
    }
    if (wt == 3) {
        for (int idx = tid; idx < 1536; idx += 256) {
            int cc2 = idx / 192, o = idx % 192;
            t2p[(size_t)cc2 * CC_SLAB + ((size_t)b * 64 + h) * 2304 + 132 * 16 + o] = 0;
        }
    }
    if (bid == 0) {
        uint32_t* z = t2p + T2P_WORDS;
        for (int idx = tid; idx < 1024; idx += 256) z[idx] = 0;
    }
}

// =====================================================================
// PASS 2 v5 (corr3): IDENTICAL to R6 except rotation p = b (batch):
//  - all blocks of an XCD share one channel-phase -> per-XCD B working
//    set 576 KB (L2-resident; 2x halo reuse becomes L2 hits; B fabric
//    traffic ~74 MB -> ~36 MB read-once)
//  - XCDs sit at 8 different phases -> chip-wide fabric demand smoothed
//    (R4's measured +10us lever, preserved at XCD granularity)
// =====================================================================
#define AS1 __attribute__((address_space(1)))
#define AS3 __attribute__((address_space(3)))

__device__ __forceinline__ void gld_lds16(const uint32_t* src, uint32_t* dst) {
    __builtin_amdgcn_global_load_lds((const AS1 void*)src, (AS3 void*)dst, 16, 0, 0);
}

#define BUF_WORDS 9216            // 24 rows x 24 cells x 16 words (36 KB)
#define DUMP_OFF  (4 * BUF_WORDS) // shared dump cell for dummy slots

__global__ __launch_bounds__(1024, 4)
void corr3(const float* __restrict__ f1, const uint32_t* __restrict__ t2p,
           const uint32_t* __restrict__ wsZ, float* __restrict__ out) {
    __shared__ uint32_t ldsB[4 * BUF_WORDS + 256];   // 148.5 KB, 1 block/CU

    const int tid  = threadIdx.x;
    const int lane = tid & 63;
    const int wh   = tid >> 6;                    // wave id == h sub-row (0..15)
    const int n15  = lane & 15;
    const int q    = lane >> 4;

    const int bid = blockIdx.x;                   // 8b x 4ht x 8wt = 256 (1/CU)
    const int b  = bid & 7;                       // XCD = batch (round-robin heuristic)
    const int ht = (bid >> 3) & 3;
    const int wt = bid >> 5;
    const int h0 = 16 * ht, w0 = 16 * wt;
    const int h  = h0 + wh;
    const int p  = b;                             // <<< THE CHANGE: phase by batch/XCD

    const float* f1b = f1 + (size_t)b * 256 * 8192;

    // ---- B staging: 24 rows x 24 cells = 576 cells = 36 slots of 1KB.
    // 48 slot positions (3/wave); sg%4==3 -> dummy (stripe->dump), keeps
    // per-wave vmcnt uniform. Addressing via u32 offsets from t2p (reg save).
    uint32_t bOff[3], ccMul[3];
    int bOffL[3];
    bool dumpf[3];
#pragma unroll
    for (int s = 0; s < 3; ++s) {
        int sg = wh * 3 + s;                      // 0..47
        bool dummy = (sg & 3) == 3;
        int rank = (sg >> 2) * 3 + (sg & 3);      // 0..35, bijective for real
        int f = rank * 16 + (lane >> 2);          // flat cell 0..575
        int r = f / 24, cidx = f % 24;            // row (halo), cell col
        int gh = h0 - 4 + r;
        int gd = (lane & 3) ^ ((cidx >> 1) & 3);  // quarter swizzle (verified)
        bool inb = !dummy && ((unsigned)gh < 64u);
        bOff[s]  = inb ? (uint32_t)((b * 64 + gh) * 2304 + (w0 + cidx) * 16 + gd * 4)
                       : (uint32_t)(T2P_WORDS + lane * 4);   // zero stripe
        ccMul[s] = inb ? (uint32_t)CC_SLAB : 0u;
        bOffL[s] = rank * 256;
        dumpf[s] = dummy;
    }

    // ---- A: lane (n15,q) covers (h, w0+n15), channels 32cc+8q+j
    const float* aBase = f1b + (size_t)h * 128 + w0 + n15;

    floatx4 acc[9][2];
#pragma unroll
    for (int di = 0; di < 9; ++di)
#pragma unroll
        for (int t = 0; t < 2; ++t)
            acc[di][t] = (floatx4){0.f, 0.f, 0.f, 0.f};

    const int rdB = n15 * 16 + ((q ^ ((n15 >> 1) & 3)) << 2);

    auto stageB = [&](int bufsel, int cc) {       // 3 gld_lds16 per wave
        uint32_t* dbase = ldsB + bufsel * BUF_WORDS;
#pragma unroll
        for (int s = 0; s < 3; ++s) {
            const uint32_t* src = t2p + (size_t)(bOff[s] + (uint32_t)cc * ccMul[s]);
            uint32_t* d = dumpf[s] ? (ldsB + DUMP_OFF) : (dbase + bOffL[s]);
            gld_lds16(src, d);
        }
    };
    auto loadA = [&](float* r, int cc) {          // 8 dword loads per lane
        const float* ap = aBase + (size_t)(32 * cc + 8 * q) * 8192;
#pragma unroll
        for (int j = 0; j < 8; ++j) r[j] = ap[(size_t)j * 8192];
    };
    auto packA = [&](const float* r) -> short8 {
        uintx4 av = {pack2(r[0], r[1]), pack2(r[2], r[3]),
                     pack2(r[4], r[5]), pack2(r[6], r[7])};
        return __builtin_bit_cast(short8, av);
    };
    auto mfma9 = [&](int bufsel, short8 a0) {
        const uint32_t* bufB = ldsB + bufsel * BUF_WORDS;
#pragma unroll
        for (int di = 0; di < 9; ++di) {
            const uint32_t* p0 = bufB + (wh + di) * 384 + rdB;   // rows 0..23
            uintx4 v0 = *(const uintx4*)p0;                      // cell n15
            uintx4 v1 = *(const uintx4*)(p0 + 128);              // cell n15+8
            short8 b0 = __builtin_bit_cast(short8, v0);
            short8 b1 = __builtin_bit_cast(short8, v1);
            acc[di][0] = __builtin_amdgcn_mfma_f32_16x16x32_bf16(a0, b0, acc[di][0], 0, 0, 0);
            acc[di][1] = __builtin_amdgcn_mfma_f32_16x16x32_bf16(a0, b1, acc[di][1], 0, 0, 0);
        }
    };

    float rA0[8], rA1[8];
#define ROT(t) (((t) + p) & 7)
#define SB __builtin_amdgcn_sched_barrier(0)

    // prologue FIFO: A0(8) B0(3) A1(8) B1(3) B2(3) = 25 outstanding
    loadA(rA0, ROT(0)); SB;
    stageB(0, ROT(0)); SB;
    loadA(rA1, ROT(1)); SB;
    stageB(1, ROT(1)); SB;
    stageB(2, ROT(2)); SB;

    // Chunk K: vmcnt drains A(K),B(K) exactly (FIFO-derived: 14,...,14,11,0).
    // Body: pack A(K); reload set for A(K+2); stage B(K+3) into the buffer
    // freed at this barrier (read at K-1); compute buf K&3.
#define CHUNK(K, VM, RS)                                                      \
    {                                                                         \
        asm volatile("s_waitcnt vmcnt(" #VM ")\n\ts_barrier" ::: "memory");   \
        short8 a0 = packA(RS);                                                \
        SB;                                                                   \
        if ((K) <= 5) loadA(RS, ROT((K) + 2));                                \
        SB;                                                                   \
        if ((K) <= 4) stageB(((K) + 3) & 3, ROT((K) + 3));                    \
        SB;                                                                   \
        mfma9((K) & 3, a0);                                                   \
    }

    CHUNK(0, 14, rA0)
    CHUNK(1, 14, rA1)
    CHUNK(2, 14, rA0)
    CHUNK(3, 14, rA1)
    CHUNK(4, 14, rA0)
    CHUNK(5, 14, rA1)
    CHUNK(6, 11, rA0)
    CHUNK(7, 0,  rA1)
#undef CHUNK
#undef ROT
#undef SB

    // ---- epilogue: band extraction (verified). dj = t*8 + n15 - mp; t1 stores n15>=8.
    const size_t base = ((size_t)b * 81) * 8192 + (size_t)h * 128 + w0;
#pragma unroll
    for (int di = 0; di < 9; ++di) {
#pragma unroll
        for (int t = 0; t < 2; ++t) {
#pragma unroll
            for (int r = 0; r < 4; ++r) {
                int mp = 4 * q + r;
                int dj = t * 8 + n15 - mp;
                if (dj >= 0 && dj <= 8 && (t == 0 || n15 >= 8)) {
                    out[base + (size_t)(di * 9 + dj) * 8192 + mp] = acc[di][t][r];
                }
            }
        }
    }
}

// =====================================================================
// FALLBACK (verified R2 kernel) — used only if workspace is too small.
// =====================================================================
#define CS 18
#define A_WORDS (8 * 16 * CS)
#define B_ROWS  13
#define B_WORDS (B_ROWS * 24 * CS)

__device__ __forceinline__ short8 frag_ld(const uint32_t* p) {
    uintx2 lo = *(const uintx2*)p;
    uintx2 hi = *(const uintx2*)(p + 2);
    uintx4 v = {lo.x, lo.y, hi.x, hi.y};
    return __builtin_bit_cast(short8, v);
}

__global__ __launch_bounds__(512, 4)
void corr_kernel(const float* __restrict__ f1, const float* __restrict__ f2,
                 float* __restrict__ out) {
    __shared__ uint32_t ldsA[2 * A_WORDS];
    __shared__ uint32_t ldsB2[2 * B_WORDS];

    const int tid  = threadIdx.x;
    const int lane = tid & 63;
    const int wh   = tid >> 6;
    const int n15  = lane & 15;
    const int q    = lane >> 4;

    const int bid    = blockIdx.x;
    const int b      = bid & 7;
    const int dihalf = (bid >> 3) & 1;
    const int ht     = (bid >> 4) & 7;
    const int wt     = bid >> 7;

    const int w0 = wt * 16;
    const int h0 = ht * 8;
    const int h  = h0 + wh;

    const int diN    = dihalf ? 4 : 5;
    const int diBase = dihalf * 5;
    const int ghBase = dihalf ? (h0 + 1) : (h0 - 4);

    const float* f1b = f1 + (size_t)b * 256 * 8192;
    const float* f2b = f2 + (size_t)b * 256 * 8192;

    const int aw4 = tid & 3, akp = (tid >> 2) & 15, arow = tid >> 6;
    int aOffG = (2 * akp) * 8192 + (h0 + arow) * 128 + (w0 + 4 * aw4);
    const int aLds = (arow * 16 + 4 * aw4) * CS + akp;

    int bOffG[3]; int bLds[3]; uint32_t bMask[3];
#pragma unroll
    for (int s = 0; s < 3; ++s) {
        int t = tid + 512 * s;
        int w4 = t % 6;
        int r2 = t / 6;
        int kp = r2 & 15, row = r2 >> 4;
        int gh = ghBase + row;
        int gw = w0 - 4 + 4 * w4;
        bool live = (t < 1152);
        bool inb  = live && ((unsigned)gh < 64u) && ((unsigned)gw < 128u);
        bOffG[s] = inb ? ((2 * kp) * 8192 + gh * 128 + gw) : 0;
        bLds[s]  = live ? ((row * 24 + 4 * w4) * CS + kp) : ((12 * 24 + (tid & 7)) * CS);
        bMask[s] = inb ? 0xFFFFFFFFu : 0u;
    }

    floatx4 acc[5][2];
#pragma unroll
    for (int dl = 0; dl < 5; ++dl)
#pragma unroll
        for (int t = 0; t < 2; ++t)
            acc[dl][t] = (floatx4){0.f, 0.f, 0.f, 0.f};

    floatx4 rA[2], rB[3][2];
    uint32_t pkA[4], pkB[12];

    auto issue = [&]() {
        rA[0] = *(const floatx4*)(f1b + aOffG);
        rA[1] = *(const floatx4*)(f1b + aOffG + 8192);
        aOffG += 32 * 8192;
#pragma unroll
        for (int s = 0; s < 3; ++s) {
            rB[s][0] = *(const floatx4*)(f2b + bOffG[s]);
            rB[s][1] = *(const floatx4*)(f2b + bOffG[s] + 8192);
            bOffG[s] += 32 * 8192;
        }
    };
    auto packall = [&]() {
#pragma unroll
        for (int i = 0; i < 4; ++i) pkA[i] = pack2(rA[0][i], rA[1][i]);
#pragma unroll
        for (int s = 0; s < 3; ++s)
#pragma unroll
            for (int i = 0; i < 4; ++i)
                pkB[4 * s + i] = pack2(rB[s][0][i], rB[s][1][i]) & bMask[s];
    };

    issue(); packall();

    for (int ch = 0; ch < 8; ++ch) {
        uint32_t* bufA = ldsA + (ch & 1) * A_WORDS;
        uint32_t* bufB = ldsB2 + (ch & 1) * B_WORDS;
#pragma unroll
        for (int i = 0; i < 4; ++i) bufA[aLds + i * CS] = pkA[i];
#pragma unroll
        for (int s = 0; s < 3; ++s)
#pragma unroll
            for (int i = 0; i < 4; ++i) bufB[bLds[s] + i * CS] = pkB[4 * s + i];
        if (ch < 7) issue();
        __syncthreads();

        const uint32_t* pa = bufA + (wh * 16 + n15) * CS + 4 * q;
        short8 a0 = frag_ld(pa);
        const uint32_t* pb = bufB + (wh * 24 + n15) * CS + 4 * q;
#pragma unroll
        for (int dl = 0; dl < 5; ++dl) {
            if (dl < diN) {
                const uint32_t* pp = pb + dl * (24 * CS);
                short8 b0 = frag_ld(pp);
                short8 b1 = frag_ld(pp + 8 * CS);
                acc[dl][0] = __builtin_amdgcn_mfma_f32_16x16x32_bf16(a0, b0, acc[dl][0], 0, 0, 0);
                acc[dl][1] = __builtin_amdgcn_mfma_f32_16x16x32_bf16(a0, b1, acc[dl][1], 0, 0, 0);
            }
        }
        if (ch < 7) packall();
    }

    const size_t base = ((size_t)b * 81) * 8192 + (size_t)h * 128 + w0;
#pragma unroll
    for (int dl = 0; dl < 5; ++dl) {
        if (dl < diN) {
            const int dio = diBase + dl;
#pragma unroll
            for (int t = 0; t < 2; ++t) {
#pragma unroll
                for (int r = 0; r < 4; ++r) {
                    int mp = 4 * q + r;
                    int dj = t * 8 + n15 - mp;
                    if (dj >= 0 && dj <= 8 && (t == 0 || n15 >= 8)) {
                        out[base + (size_t)(dio * 9 + dj) * 8192 + mp] = acc[dl][t][r];
                    }
                }
            }
        }
    }
}

extern "C" void kernel_launch(void* const* d_in, const int* in_sizes, int n_in,
                              void* d_out, int out_size, void* d_ws, size_t ws_size,
                              hipStream_t stream) {
    const float* f1 = (const float*)d_in[0];
    const float* f2 = (const float*)d_in[1];
    float* out = (float*)d_out;
    if (ws_size >= WS_NEED && d_ws != nullptr) {
        uint32_t* t2p = (uint32_t*)d_ws;
        transpose_f2<<<dim3(2048), dim3(256), 0, stream>>>(f2, t2p);
        corr3<<<dim3(256), dim3(1024), 0, stream>>>(f1, t2p, t2p + T2P_WORDS, out);
    } else {
        corr_kernel<<<dim3(1024), dim3(512), 0, stream>>>(f1, f2, out);
    }
}